// Round 2
// baseline (38286.664 us; speedup 1.0000x reference)
//
#include <hip/hip_runtime.h>
#include <cstdint>
#include <cstddef>

#define HID   512
#define NB    64
#define SEQT  1000
#define NENT  550

#define NWG   256   // 128 wgs per layer
#define NTHR  256
#define SLICES 128  // wgs per layer; each owns 4 hidden units (16 gate cols)
#define KTOT  1024
#define KCH   128   // k-chunk (floats)
#define NCH   8     // 1024 / 128
#define IP    132   // padded LDS pitch

typedef unsigned long long ull;

__device__ __forceinline__ float sigm(float x) {
  x = fminf(fmaxf(x, -30.f), 30.f);
  return 1.f / (1.f + __expf(-x));
}
__device__ __forceinline__ float tanh_f(float x) {
  x = fminf(fmaxf(x, -15.f), 15.f);
  float e = __expf(2.f * x);
  return (e - 1.f) / (e + 1.f);
}
// write-through to LLC (never dirties per-XCD L2) — producer side of exchange
__device__ __forceinline__ void st_llc(float* p, float v) {
  __hip_atomic_store(p, v, __ATOMIC_RELAXED, __HIP_MEMORY_SCOPE_AGENT);
}

// One-time repack: Wp[((L*SLICES+sl)*KTOT + k)*4 + g] = W_L[k][g*512 + sl*4 .. +3]
// Each wg's slice becomes a dense 64 KB block -> perfectly coalesced LDS preload.
__global__ void __launch_bounds__(256)
pack_w(const float* __restrict__ W0, const float* __restrict__ W1,
       float4* __restrict__ Wp)
{
  const unsigned idx = blockIdx.x * 256u + threadIdx.x;  // over 2*128*1024*4
  const int g  = idx & 3;
  const int k  = (idx >> 2) & (KTOT - 1);
  const int sl = (idx >> 12) & (SLICES - 1);
  const int L  = idx >> 19;
  const float* W = L ? W1 : W0;
  Wp[idx] = *(const float4*)(W + (size_t)k * 2048 + g * HID + sl * 4);
}

__global__ void __launch_bounds__(NTHR, 1)
lstm_persistent(const int* __restrict__ tok, const int* __restrict__ len,
                const float* __restrict__ emb,
                const float* __restrict__ W0, const float* __restrict__ b0,
                const float* __restrict__ W1, const float* __restrict__ b1,
                const float* __restrict__ Wout, const float* __restrict__ bout,
                float* __restrict__ out, unsigned char* __restrict__ ws,
                const float4* __restrict__ Wp, int packed)
{
  // LDS budget: 64 KB weights + 66 KB input staging + 4 KB exchange = ~137 KB (<160)
  __shared__ float4 Wl[KTOT * 4];    // [k][g] float4 = this wg's whole weight slice
  __shared__ float inl[2][NB][IP];   // double-buffered input staging (~66 KB)
  __shared__ float gl[NB][16];       // gate exchange
  __shared__ float bl[16];
  __shared__ int   s_maxlen;

  const int tid = threadIdx.x;
  const int wg  = blockIdx.x;
  const int L   = wg >> 7;              // 0: layer0, 1: layer1
  const int sl  = wg & (SLICES - 1);    // slice (4 hidden units)

  unsigned* cnt = (unsigned*)ws;
  float* h0b   = (float*)(ws + 256);        // [2][NB][HID]
  float* h1b   = h0b + 2 * NB * HID;
  float* y0b   = h1b + 2 * NB * HID;
  float* lastb = y0b + 2 * NB * HID;        // [NB][HID]

  const float* Wsrc = L ? W1 : W0;
  const float* bsrc = L ? b1 : b0;

  const int b   = tid & 63;   // lane = batch (compute + staging row)
  const int seg = tid >> 6;   // wave id = gate g (0..3); also staging k-segment
  const int ub  = tid >> 2;   // update batch
  const int uu  = tid & 3;    // update unit within slice
  const int gu  = sl * 4 + uu;

  if (tid < 16) bl[tid] = bsrc[(tid >> 2) * HID + sl * 4 + (tid & 3)];
  if (tid < 64) {
    int l = len[tid];
    #pragma unroll
    for (int off = 32; off; off >>= 1) l = max(l, __shfl_xor(l, off));
    if (tid == 0) s_maxlen = l;
  }
  const int len_b  = len[b];
  const int len_ub = len[ub];

  // ---- one-time weight preload into LDS (reused for all 1000 timesteps) ----
  if (packed) {
    const float4* wsrc = Wp + (size_t)(L * SLICES + sl) * KTOT * 4;
    #pragma unroll 4
    for (int i = tid; i < KTOT * 4; i += NTHR)
      Wl[i] = wsrc[i];                      // dense 64 KB block, fully coalesced
  } else {
    for (int i = tid; i < KTOT * 4; i += NTHR) {
      const int k = i >> 2, g = i & 3;
      Wl[i] = *(const float4*)(Wsrc + (size_t)k * 2048 + g * HID + sl * 4);
    }
  }
  __syncthreads();
  const int maxlen = s_maxlen;

  float c_st = 0.f, h_st = 0.f;
  unsigned target = 0;

  for (int r = 0; r <= maxlen; ++r) {
    const bool active = (L == 0) ? (r < maxlen) : (r >= 1);
    if (active) {
      const int t = (L == 0) ? r : (r - 1);
      const bool aliveS = (t < len_b);

      const float* hprev = (L ? h1b : h0b) + ((r + 1) & 1) * NB * HID + b * HID;
      const float* xsrc  = (L == 0)
          ? (emb + (size_t)tok[b * SEQT + t] * HID)
          : (y0b + ((r + 1) & 1) * NB * HID + b * HID);

      // ---- staging (thread stages row b, floats [seg*32, seg*32+32)) ----
      // All sources are plain CACHED loads now: freshness of the exchange
      // buffers is guaranteed by the per-round agent-acquire fence (buffer_inv)
      // executed after the grid barrier. Within a round, ~32 wgs per XCD share
      // each exchange line via L2 instead of 128x re-reading the LLC.
      ull v[16];
      auto stage = [&](int c) {
        if (!aliveS) return;
        const float* src = ((c < 4) ? (xsrc + c * KCH) : (hprev + (c - 4) * KCH)) + seg * 32;
        #pragma unroll
        for (int i = 0; i < 16; ++i) v[i] = *(const ull*)(src + 2 * i);
      };
      auto wr = [&](int c) {
        if (!aliveS) return;
        float* dst = &inl[c & 1][b][seg * 32];
        #pragma unroll
        for (int i = 0; i < 16; ++i) *(ull*)(dst + 2 * i) = v[i];
      };

      float a0 = 0.f, a1 = 0.f, a2 = 0.f, a3 = 0.f;
      // compute: weights from LDS (wave-uniform broadcast reads, never evicted)
      auto comp = [&](int c) {
        const float* row = &inl[c & 1][b][0];
        const float4* wb = Wl + (size_t)c * KCH * 4 + seg;
        #pragma unroll 4
        for (int k = 0; k < KCH; k += 4) {
          const float4 iv = *(const float4*)(row + k);
          const float4 w0 = wb[(k + 0) * 4];
          const float4 w1 = wb[(k + 1) * 4];
          const float4 w2 = wb[(k + 2) * 4];
          const float4 w3 = wb[(k + 3) * 4];
          a0 = fmaf(iv.x, w0.x, a0); a1 = fmaf(iv.x, w0.y, a1);
          a2 = fmaf(iv.x, w0.z, a2); a3 = fmaf(iv.x, w0.w, a3);
          a0 = fmaf(iv.y, w1.x, a0); a1 = fmaf(iv.y, w1.y, a1);
          a2 = fmaf(iv.y, w1.z, a2); a3 = fmaf(iv.y, w1.w, a3);
          a0 = fmaf(iv.z, w2.x, a0); a1 = fmaf(iv.z, w2.y, a1);
          a2 = fmaf(iv.z, w2.z, a2); a3 = fmaf(iv.z, w2.w, a3);
          a0 = fmaf(iv.w, w3.x, a0); a1 = fmaf(iv.w, w3.y, a1);
          a2 = fmaf(iv.w, w3.z, a2); a3 = fmaf(iv.w, w3.w, a3);
        }
      };

      stage(0);
      wr(0);
      __syncthreads();
      for (int c = 0; c < NCH; ++c) {
        if (c < NCH - 1) stage(c + 1);     // issue loads (hidden under compute)
        comp(c);
        if (c < NCH - 1) wr(c + 1);        // LDS write after compute; loads landed
        __syncthreads();
      }

      // ---- gate exchange: wave seg holds gate g=seg for units 0..3 of (b) ----
      *(float4*)&gl[b][seg << 2] = make_float4(a0, a1, a2, a3);
      __syncthreads();

      // ---- cell update: thread (ub, uu) ----
      const bool alive = (t < len_ub);
      float gi = gl[ub][uu]      + bl[uu];
      float gj = gl[ub][4 + uu]  + bl[4 + uu];
      float gf = gl[ub][8 + uu]  + bl[8 + uu];
      float go = gl[ub][12 + uu] + bl[12 + uu];
      float cn = sigm(gf) * c_st + sigm(gi) * tanh_f(gj);
      float hn = sigm(go) * tanh_f(cn);
      if (alive) { c_st = cn; h_st = hn; }
      float* hb = (L ? h1b : h0b) + (r & 1) * NB * HID;
      st_llc(&hb[ub * HID + gu], h_st);
      if (L == 0) {
        st_llc(&y0b[(r & 1) * NB * HID + ub * HID + gu], alive ? hn : 0.f);
      } else if (t == len_ub - 1) {
        st_llc(&lastb[ub * HID + gu], hn);
      }
      __syncthreads();
    }

    // ---- grid barrier: WT stores already at LLC; arrival via counter ----
    target += NWG;
    asm volatile("s_waitcnt vmcnt(0) lgkmcnt(0)" ::: "memory");
    __syncthreads();
    if (tid == 0) {
      __hip_atomic_fetch_add(cnt, 1u, __ATOMIC_RELAXED, __HIP_MEMORY_SCOPE_AGENT);
      while (__hip_atomic_load(cnt, __ATOMIC_RELAXED, __HIP_MEMORY_SCOPE_AGENT) < target)
        __builtin_amdgcn_s_sleep(1);
    }
    __syncthreads();
    // acquire: invalidate stale L1/L2 copies of the exchange buffers so the
    // plain cached staging loads of the next round see this round's stores
    __builtin_amdgcn_fence(__ATOMIC_ACQUIRE, "agent");
  }

  // ---- epilogue: logits = last @ Wout + bout (cached reads; fence above) ----
  const int go_ = wg * NTHR + tid;
  if (go_ < NB * NENT) {
    const int bb = go_ / NENT;
    const int e  = go_ - bb * NENT;
    const float* lrow = lastb + bb * HID;
    float s = bout[e];
    #pragma unroll 8
    for (int k = 0; k < HID; ++k)
      s = fmaf(lrow[k], Wout[k * NENT + e], s);
    out[go_] = s;
  }
}

extern "C" void kernel_launch(void* const* d_in, const int* in_sizes, int n_in,
                              void* d_out, int out_size, void* d_ws, size_t ws_size,
                              hipStream_t stream) {
  (void)in_sizes; (void)n_in; (void)out_size;
  const int*   tok  = (const int*)d_in[0];
  const int*   len  = (const int*)d_in[1];
  const float* emb  = (const float*)d_in[2];
  const float* W0   = (const float*)d_in[3];
  const float* b0   = (const float*)d_in[4];
  const float* W1   = (const float*)d_in[5];
  const float* b1   = (const float*)d_in[6];
  const float* Wout = (const float*)d_in[7];
  const float* bout = (const float*)d_in[8];
  float* out = (float*)d_out;
  unsigned char* ws = (unsigned char*)d_ws;

  // ws layout: [0,256) counter | exchange (7*128 KB) | packed W (16 MB, 256-aligned)
  const size_t zbytes   = 256 + (size_t)7 * NB * HID * sizeof(float);
  const size_t pack_off = (zbytes + 255) & ~(size_t)255;
  const size_t pack_sz  = (size_t)2 * SLICES * KTOT * 4 * sizeof(float4); // 16 MB
  const int    packed   = (ws_size >= pack_off + pack_sz) ? 1 : 0;
  float4* Wp = (float4*)(ws + pack_off);

  hipMemsetAsync(ws, 0, zbytes, stream);
  if (packed) {
    const int n4 = 2 * SLICES * KTOT * 4;           // 1,048,576 float4
    pack_w<<<n4 / 256, 256, 0, stream>>>(W0, W1, Wp);
  }

  void* args[] = {(void*)&tok, (void*)&len, (void*)&emb, (void*)&W0, (void*)&b0,
                  (void*)&W1, (void*)&b1, (void*)&Wout, (void*)&bout,
                  (void*)&out, (void*)&ws, (void*)&Wp, (void*)&packed};
  hipLaunchCooperativeKernel((const void*)lstm_persistent, dim3(NWG), dim3(NTHR),
                             args, 0, stream);
}

// Round 3
// 29446.451 us; speedup vs baseline: 1.3002x; 1.3002x over previous
//
#include <hip/hip_runtime.h>
#include <cstdint>
#include <cstddef>

#define HID   512
#define NB    64
#define SEQT  1000
#define NENT  550

#define NWG   256   // 128 wgs per layer
#define NTHR  256
#define SLICES 128  // wgs per layer; each owns 4 hidden units (16 gate cols)
#define KTOT  1024
#define KCH   128   // k-chunk (floats)
#define NCH   8     // 1024 / 128
#define IP    132   // padded LDS pitch

typedef unsigned long long ull;
typedef float f32x4 __attribute__((ext_vector_type(4)));

__device__ __forceinline__ float sigm(float x) {
  x = fminf(fmaxf(x, -30.f), 30.f);
  return 1.f / (1.f + __expf(-x));
}
__device__ __forceinline__ float tanh_f(float x) {
  x = fminf(fmaxf(x, -15.f), 15.f);
  float e = __expf(2.f * x);
  return (e - 1.f) / (e + 1.f);
}
// write-through to LLC (never dirties per-XCD L2) — producer side of exchange
__device__ __forceinline__ void st_llc(float* p, float v) {
  __hip_atomic_store(p, v, __ATOMIC_RELAXED, __HIP_MEMORY_SCOPE_AGENT);
}
__device__ __forceinline__ float ld_llc4(const float* p) {
  return __hip_atomic_load(p, __ATOMIC_RELAXED, __HIP_MEMORY_SCOPE_AGENT);
}

// 8x 16B loads, manually vmcnt-counted (asm so the compiler's waitcnt pass
// can't insert a defeating vmcnt(0); HK T3/T4 pattern).
// MOD "" = cached (read-only emb); MOD " sc1 nt" = device-scope, no-allocate
// (LLC-coherent exchange reads; matches the semantics of the proven
// __hip_atomic_load agent path but at 16B granularity -> half the requests).
#define LD8(V, SRC, MOD)                                                  \
  asm volatile(                                                           \
    "global_load_dwordx4 %0, %8, off" MOD "\n\t"                          \
    "global_load_dwordx4 %1, %8, off offset:16" MOD "\n\t"                \
    "global_load_dwordx4 %2, %8, off offset:32" MOD "\n\t"                \
    "global_load_dwordx4 %3, %8, off offset:48" MOD "\n\t"                \
    "global_load_dwordx4 %4, %8, off offset:64" MOD "\n\t"                \
    "global_load_dwordx4 %5, %8, off offset:80" MOD "\n\t"                \
    "global_load_dwordx4 %6, %8, off offset:96" MOD "\n\t"                \
    "global_load_dwordx4 %7, %8, off offset:112" MOD "\n\t"               \
    : "=&v"((V)[0]), "=&v"((V)[1]), "=&v"((V)[2]), "=&v"((V)[3]),         \
      "=&v"((V)[4]), "=&v"((V)[5]), "=&v"((V)[6]), "=&v"((V)[7])          \
    : "v"(SRC) : "memory")

#define VW8  asm volatile("s_waitcnt vmcnt(8)" ::: "memory")
#define VW0  asm volatile("s_waitcnt vmcnt(0)" ::: "memory")
// raw barrier: only LDS ops must drain (ds_write visibility); global loads
// stay in flight across it (this is what __syncthreads forbids)
#define LBAR do { asm volatile("s_waitcnt lgkmcnt(0)" ::: "memory");      \
                  __builtin_amdgcn_s_barrier(); } while (0)

// One-time repack: Wp[((L*SLICES+sl)*KTOT + k)*4 + g] = W_L[k][g*512 + sl*4 .. +3]
__global__ void __launch_bounds__(256)
pack_w(const float* __restrict__ W0, const float* __restrict__ W1,
       float4* __restrict__ Wp)
{
  const unsigned idx = blockIdx.x * 256u + threadIdx.x;  // over 2*128*1024*4
  const int g  = idx & 3;
  const int k  = (idx >> 2) & (KTOT - 1);
  const int sl = (idx >> 12) & (SLICES - 1);
  const int L  = idx >> 19;
  const float* W = L ? W1 : W0;
  Wp[idx] = *(const float4*)(W + (size_t)k * 2048 + g * HID + sl * 4);
}

__global__ void __launch_bounds__(NTHR, 1)
lstm_persistent(const int* __restrict__ tok, const int* __restrict__ len,
                const float* __restrict__ emb,
                const float* __restrict__ W0, const float* __restrict__ b0,
                const float* __restrict__ W1, const float* __restrict__ b1,
                const float* __restrict__ Wout, const float* __restrict__ bout,
                float* __restrict__ out, unsigned char* __restrict__ ws,
                const float4* __restrict__ Wp, int packed)
{
  // LDS: 64 KB weights + 66 KB input staging + 4 KB exchange = ~137 KB (<160)
  __shared__ float4 Wl[KTOT * 4];    // [k][g] float4 = this wg's whole weight slice
  __shared__ float inl[2][NB][IP];   // double-buffered input staging
  __shared__ float gl[NB][16];       // gate exchange
  __shared__ float bl[16];
  __shared__ int   s_maxlen;

  const int tid = threadIdx.x;
  const int wg  = blockIdx.x;
  const int L   = wg >> 7;              // 0: layer0, 1: layer1
  const int sl  = wg & (SLICES - 1);    // slice (4 hidden units)

  unsigned* cnt = (unsigned*)ws;
  float* h0b   = (float*)(ws + 256);        // [2][NB][HID]
  float* h1b   = h0b + 2 * NB * HID;
  float* y0b   = h1b + 2 * NB * HID;
  float* lastb = y0b + 2 * NB * HID;        // [NB][HID]

  const float* Wsrc = L ? W1 : W0;
  const float* bsrc = L ? b1 : b0;

  const int b   = tid & 63;   // lane = batch (compute + staging row)
  const int seg = tid >> 6;   // wave id = gate g (0..3); also staging k-segment
  const int ub  = tid >> 2;   // update batch
  const int uu  = tid & 3;    // update unit within slice
  const int gu  = sl * 4 + uu;

  if (tid < 16) bl[tid] = bsrc[(tid >> 2) * HID + sl * 4 + (tid & 3)];
  if (tid < 64) {
    int l = len[tid];
    #pragma unroll
    for (int off = 32; off; off >>= 1) l = max(l, __shfl_xor(l, off));
    if (tid == 0) s_maxlen = l;
  }
  const int len_b  = len[b];
  const int len_ub = len[ub];

  // ---- one-time weight preload into LDS (reused for all 1000 timesteps) ----
  if (packed) {
    const float4* wsrc = Wp + (size_t)(L * SLICES + sl) * KTOT * 4;
    #pragma unroll 4
    for (int i = tid; i < KTOT * 4; i += NTHR)
      Wl[i] = wsrc[i];
  } else {
    for (int i = tid; i < KTOT * 4; i += NTHR) {
      const int k = i >> 2, g = i & 3;
      Wl[i] = *(const float4*)(Wsrc + (size_t)k * 2048 + g * HID + sl * 4);
    }
  }
  __syncthreads();
  const int maxlen = s_maxlen;

  float c_st = 0.f, h_st = 0.f;
  unsigned target = 0;

  for (int r = 0; r <= maxlen; ++r) {
    const bool active = (L == 0) ? (r < maxlen) : (r >= 1);
    if (active) {
      const int t = (L == 0) ? r : (r - 1);
      const bool aliveS = (t < len_b);

      const float* hprev = (L ? h1b : h0b) + ((r + 1) & 1) * NB * HID + b * HID;
      const float* xsrc  = (L == 0)
          ? (emb + (size_t)tok[b * SEQT + t] * HID)
          : (y0b + ((r + 1) & 1) * NB * HID + b * HID);

      // issue 8x16B stage loads for chunk cc into V (exec-masked; aliveS is
      // round-constant so per-wave vmcnt accounting stays exact)
      auto stageTo = [&](f32x4* V, int cc) {
        if (!aliveS) return;
        const float* src =
            ((cc < 4) ? (xsrc + cc * KCH) : (hprev + (cc - 4) * KCH)) + seg * 32;
        if (cc < 4 && L == 0) { LD8(V, src, ""); }         // emb: cached
        else                  { LD8(V, src, " sc1 nt"); }  // exchange: LLC
      };
      auto wrTo = [&](int k, const f32x4* V) {
        if (!aliveS) return;
        f32x4* dst = (f32x4*)&inl[k & 1][b][seg * 32];
        #pragma unroll
        for (int i = 0; i < 8; ++i) dst[i] = V[i];
      };

      float a0 = 0.f, a1 = 0.f, a2 = 0.f, a3 = 0.f;
      // weights from LDS (wave-uniform broadcast reads, never evicted)
      auto comp = [&](int c) {
        const float* row = &inl[c & 1][b][0];
        const float4* wb = Wl + (size_t)c * KCH * 4 + seg;
        #pragma unroll 4
        for (int k = 0; k < KCH; k += 4) {
          const f32x4 iv = *(const f32x4*)(row + k);
          const float4 w0 = wb[(k + 0) * 4];
          const float4 w1 = wb[(k + 1) * 4];
          const float4 w2 = wb[(k + 2) * 4];
          const float4 w3 = wb[(k + 3) * 4];
          a0 = fmaf(iv[0], w0.x, a0); a1 = fmaf(iv[0], w0.y, a1);
          a2 = fmaf(iv[0], w0.z, a2); a3 = fmaf(iv[0], w0.w, a3);
          a0 = fmaf(iv[1], w1.x, a0); a1 = fmaf(iv[1], w1.y, a1);
          a2 = fmaf(iv[1], w1.z, a2); a3 = fmaf(iv[1], w1.w, a3);
          a0 = fmaf(iv[2], w2.x, a0); a1 = fmaf(iv[2], w2.y, a1);
          a2 = fmaf(iv[2], w2.z, a2); a3 = fmaf(iv[2], w2.w, a3);
          a0 = fmaf(iv[3], w3.x, a0); a1 = fmaf(iv[3], w3.y, a1);
          a2 = fmaf(iv[3], w3.z, a2); a3 = fmaf(iv[3], w3.w, a3);
        }
      };

      // ---- 2-deep software pipeline: batch k lives in (k&1 ? vB : vA) ----
      f32x4 vA[8], vB[8];
      stageTo(vA, 0);                 // vmcnt: 8
      stageTo(vB, 1);                 // vmcnt: 16
      VW8;                            // batch 0 landed
      wrTo(0, vA);
      LBAR;
      for (int c = 0; c < 6; c += 2) {
        stageTo(vA, c + 2);           // 16 in flight
        comp(c);
        VW8;                          // batch c+1 landed (c+2 still out)
        wrTo(c + 1, vB);
        LBAR;
        stageTo(vB, c + 3);
        comp(c + 1);
        VW8;                          // batch c+2 landed (c+3 still out)
        wrTo(c + 2, vA);
        LBAR;
      }
      comp(6);
      VW0;                            // drain batch 7
      wrTo(7, vB);
      LBAR;
      comp(7);

      // ---- gate exchange: wave seg holds gate g=seg for units 0..3 of (b) ----
      *(float4*)&gl[b][seg << 2] = make_float4(a0, a1, a2, a3);
      LBAR;

      // ---- cell update: thread (ub, uu) ----
      const bool alive = (t < len_ub);
      float gi = gl[ub][uu]      + bl[uu];
      float gj = gl[ub][4 + uu]  + bl[4 + uu];
      float gf = gl[ub][8 + uu]  + bl[8 + uu];
      float go = gl[ub][12 + uu] + bl[12 + uu];
      float cn = sigm(gf) * c_st + sigm(gi) * tanh_f(gj);
      float hn = sigm(go) * tanh_f(cn);
      if (alive) { c_st = cn; h_st = hn; }
      float* hb = (L ? h1b : h0b) + (r & 1) * NB * HID;
      st_llc(&hb[ub * HID + gu], h_st);
      if (L == 0) {
        st_llc(&y0b[(r & 1) * NB * HID + ub * HID + gu], alive ? hn : 0.f);
      } else if (t == len_ub - 1) {
        st_llc(&lastb[ub * HID + gu], hn);
      }
    }

    // ---- fence-free grid barrier: WT stores already at LLC; readers bypass L2 ----
    target += NWG;
    asm volatile("s_waitcnt vmcnt(0) lgkmcnt(0)" ::: "memory");
    __syncthreads();
    if (tid == 0) {
      __hip_atomic_fetch_add(cnt, 1u, __ATOMIC_RELAXED, __HIP_MEMORY_SCOPE_AGENT);
      while (__hip_atomic_load(cnt, __ATOMIC_RELAXED, __HIP_MEMORY_SCOPE_AGENT) < target)
        __builtin_amdgcn_s_sleep(1);
    }
    __syncthreads();
  }

  // ---- epilogue: logits = last @ Wout + bout ----
  const int go_ = wg * NTHR + tid;
  if (go_ < NB * NENT) {
    const int bb = go_ / NENT;
    const int e  = go_ - bb * NENT;
    const float* lrow = lastb + bb * HID;
    float s = bout[e];
    #pragma unroll 8
    for (int k = 0; k < HID; ++k)
      s = fmaf(ld_llc4(lrow + k), Wout[k * NENT + e], s);
    out[go_] = s;
  }
}

extern "C" void kernel_launch(void* const* d_in, const int* in_sizes, int n_in,
                              void* d_out, int out_size, void* d_ws, size_t ws_size,
                              hipStream_t stream) {
  (void)in_sizes; (void)n_in; (void)out_size;
  const int*   tok  = (const int*)d_in[0];
  const int*   len  = (const int*)d_in[1];
  const float* emb  = (const float*)d_in[2];
  const float* W0   = (const float*)d_in[3];
  const float* b0   = (const float*)d_in[4];
  const float* W1   = (const float*)d_in[5];
  const float* b1   = (const float*)d_in[6];
  const float* Wout = (const float*)d_in[7];
  const float* bout = (const float*)d_in[8];
  float* out = (float*)d_out;
  unsigned char* ws = (unsigned char*)d_ws;

  // ws layout: [0,256) counter | exchange (7*128 KB) | packed W (16 MB, 256-aligned)
  const size_t zbytes   = 256 + (size_t)7 * NB * HID * sizeof(float);
  const size_t pack_off = (zbytes + 255) & ~(size_t)255;
  const size_t pack_sz  = (size_t)2 * SLICES * KTOT * 4 * sizeof(float4); // 16 MB
  const int    packed   = (ws_size >= pack_off + pack_sz) ? 1 : 0;
  float4* Wp = (float4*)(ws + pack_off);

  hipMemsetAsync(ws, 0, zbytes, stream);
  if (packed) {
    const int n4 = 2 * SLICES * KTOT * 4;           // 1,048,576 float4
    pack_w<<<n4 / 256, 256, 0, stream>>>(W0, W1, Wp);
  }

  void* args[] = {(void*)&tok, (void*)&len, (void*)&emb, (void*)&W0, (void*)&b0,
                  (void*)&W1, (void*)&b1, (void*)&Wout, (void*)&bout,
                  (void*)&out, (void*)&ws, (void*)&Wp, (void*)&packed};
  hipLaunchCooperativeKernel((const void*)lstm_persistent, dim3(NWG), dim3(NTHR),
                             args, 0, stream);
}